// Round 17
// baseline (600.763 us; speedup 1.0000x reference)
//
#include <hip/hip_runtime.h>
#include <math.h>

#define NPATCH 100000
#define CDIM   256
#define NMOOD  64
#define NGENRE 256
#define NSUB   512
#define NLBL   832          // 64+256+512
#define KTOP   9
#define NGRPTOT 6250        // NPATCH/16

// ---- f32 fallback screen constants (R4, known-green) ----
#define NCHUNK 39
#define CHUNK  2624
#define BLK    64
#define KC     32
#define KP     12

// ---- MFMA screen constants ----
#define PBLK4  992          // patches per chunk (62 groups)
#define NCH4   101          // 101*992 = 100192 >= 100000
#define SL4    4            // per-lane list depth (per label-set)
#define KPS4   9            // per-(label,chunk) stored candidates
#define NCAND  192          // merge candidates (64x12 -> 16x12)

typedef __attribute__((ext_vector_type(8))) short bf16x8;
typedef __attribute__((ext_vector_type(8))) unsigned short u16x8;
typedef __attribute__((ext_vector_type(4))) float f32x4;

// ---------------- serial top-k insert (ascending by (val,idx)) --------------

template <int K>
__device__ __forceinline__ void tk_insert(float (&v)[K], int (&ii)[K],
                                          float s, int idx) {
  if (s < v[K - 1] || (s == v[K - 1] && idx < ii[K - 1])) {
    v[K - 1] = s; ii[K - 1] = idx;
#pragma unroll
    for (int t = K - 1; t > 0; --t) {
      bool sw = (v[t] < v[t - 1]) || (v[t] == v[t - 1] && ii[t] < ii[t - 1]);
      if (sw) {
        float fv = v[t]; v[t] = v[t - 1]; v[t - 1] = fv;
        int fi = ii[t]; ii[t] = ii[t - 1]; ii[t - 1] = fi;
      }
    }
  }
}

// fast screen insert: branch-free, NO idx tie-break (ascending-idx processing
// keeps lower idx on equal keys; exact re-rank downstream finalizes order).

template <int K>
__device__ __forceinline__ void tk_fast(float (&v)[K], int (&ii)[K],
                                        float s, int idx) {
  bool ins = s < v[K - 1];
  v[K - 1] = ins ? s : v[K - 1];
  ii[K - 1] = ins ? idx : ii[K - 1];
#pragma unroll
  for (int t = K - 1; t > 0; --t) {
    bool sw = v[t] < v[t - 1];
    float a0 = sw ? v[t] : v[t - 1];
    float a1 = sw ? v[t - 1] : v[t];
    int b0 = sw ? ii[t] : ii[t - 1];
    int b1 = sw ? ii[t - 1] : ii[t];
    v[t - 1] = a0; v[t] = a1; ii[t - 1] = b0; ii[t] = b1;
  }
}

// ------ numpy-pairwise sum of squares over 256 contiguous floats ------------

__device__ float np_sq256(const float* a) {
  float b0, b1;
  {
    float r[8];
#pragma unroll
    for (int i = 0; i < 8; ++i) { float x = a[i]; r[i] = __fmul_rn(x, x); }
    for (int j = 8; j < 128; j += 8)
#pragma unroll
      for (int i = 0; i < 8; ++i) {
        float x = a[j + i];
        r[i] = __fadd_rn(r[i], __fmul_rn(x, x));
      }
    b0 = __fadd_rn(__fadd_rn(__fadd_rn(r[0], r[1]), __fadd_rn(r[2], r[3])),
                   __fadd_rn(__fadd_rn(r[4], r[5]), __fadd_rn(r[6], r[7])));
  }
  {
    float r[8];
#pragma unroll
    for (int i = 0; i < 8; ++i) { float x = a[128 + i]; r[i] = __fmul_rn(x, x); }
    for (int j = 8; j < 128; j += 8)
#pragma unroll
      for (int i = 0; i < 8; ++i) {
        float x = a[128 + j + i];
        r[i] = __fadd_rn(r[i], __fmul_rn(x, x));
      }
    b1 = __fadd_rn(__fadd_rn(__fadd_rn(r[0], r[1]), __fadd_rn(r[2], r[3])),
                   __fadd_rn(__fadd_rn(r[4], r[5]), __fadd_rn(r[6], r[7])));
  }
  return __fadd_rn(b0, b1);
}

__device__ __forceinline__ float np_key(float ln, float dot, float pn) {
  return __fadd_rn(__fsub_rn(ln, __fmul_rn(2.f, dot)), pn);
}

__device__ __forceinline__ unsigned short f2bf(float x) {
  unsigned u = __float_as_uint(x);
  return (unsigned short)((u + 0x7fffu + ((u >> 16) & 1u)) >> 16);
}

// ---------------- kernel: fused prep (labels + patches) ---------------------

__global__ __launch_bounds__(256) void k_prep3(
    const float* __restrict__ src, const float* __restrict__ mood,
    const float* __restrict__ genre, const float* __restrict__ sub,
    unsigned short* __restrict__ packed, float* __restrict__ norms,
    float* __restrict__ lbl, unsigned short* __restrict__ lblbf,
    float* __restrict__ lnorm) {
  __shared__ float lds[16][260];
  const int tid = threadIdx.x;
  const int w = tid >> 6, l = tid & 63;
  const int rr = l >> 4;            // norm row within wave quad
  const int h = (l >> 3) & 1;       // 128-half
  const int i = l & 7;              // np accumulator class
  const int col = l & 15, kg = l >> 4;  // pack coords

  if (blockIdx.x < NLBL / 16) {
    const int row = blockIdx.x * 16 + w * 4;
#pragma unroll
    for (int q = 0; q < 4; ++q) {
      int r = row + q;
      const float* srcr = (r < NMOOD) ? &mood[(size_t)r * CDIM]
                        : (r < NMOOD + NGENRE) ? &genre[(size_t)(r - NMOOD) * CDIM]
                        : &sub[(size_t)(r - NMOOD - NGENRE) * CDIM];
      float4 v = *(const float4*)&srcr[l * 4];
      *(float4*)&lbl[(size_t)r * CDIM + l * 4] = v;
      ushort4 o = make_ushort4(f2bf(v.x), f2bf(v.y), f2bf(v.z), f2bf(v.w));
      *(ushort4*)&lblbf[(size_t)r * CDIM + l * 4] = o;
      lds[w * 4 + q][l * 4 + 0] = v.x; lds[w * 4 + q][l * 4 + 1] = v.y;
      lds[w * 4 + q][l * 4 + 2] = v.z; lds[w * 4 + q][l * 4 + 3] = v.w;
    }
    __syncthreads();
    {
      const float* a = &lds[w * 4 + rr][h * 128];
      float x = a[i];
      float acc = __fmul_rn(x, x);
#pragma unroll
      for (int j = 1; j < 16; ++j) {
        float y = a[j * 8 + i];
        acc = __fadd_rn(acc, __fmul_rn(y, y));
      }
      float t = __fadd_rn(acc, __shfl_xor(acc, 1));
      t = __fadd_rn(t, __shfl_xor(t, 2));
      t = __fadd_rn(t, __shfl_xor(t, 4));
      float o = __shfl_xor(t, 8);
      if (h == 0 && i == 0) lnorm[row + rr] = __fadd_rn(t, o);
    }
  }

  for (int gg = blockIdx.x; gg < NGRPTOT; gg += gridDim.x) {
    const int base = gg * 16;       // 6250*16 == 100000: no partial groups
    __syncthreads();                // protect lds reuse
#pragma unroll
    for (int q = 0; q < 4; ++q) {
      int r = base + w * 4 + q;
      float4 v = *(const float4*)&src[(size_t)r * CDIM + l * 4];
      lds[w * 4 + q][l * 4 + 0] = v.x; lds[w * 4 + q][l * 4 + 1] = v.y;
      lds[w * 4 + q][l * 4 + 2] = v.z; lds[w * 4 + q][l * 4 + 3] = v.w;
    }
    __syncthreads();
    {
      const float* a = &lds[w * 4 + rr][h * 128];
      float x = a[i];
      float acc = __fmul_rn(x, x);
#pragma unroll
      for (int j = 1; j < 16; ++j) {
        float y = a[j * 8 + i];
        acc = __fadd_rn(acc, __fmul_rn(y, y));
      }
      float t = __fadd_rn(acc, __shfl_xor(acc, 1));
      t = __fadd_rn(t, __shfl_xor(t, 2));
      t = __fadd_rn(t, __shfl_xor(t, 4));
      float o = __shfl_xor(t, 8);
      if (h == 0 && i == 0) norms[base + w * 4 + rr] = __fadd_rn(t, o);
    }
#pragma unroll
    for (int pass = 0; pass < 2; ++pass) {
      int kk = w + 4 * pass;
      const float* a = &lds[col][kg * 8 + kk * 32];
      u16x8 o;
#pragma unroll
      for (int j = 0; j < 8; ++j) o[j] = f2bf(a[j]);
      *(u16x8*)&packed[((size_t)gg * 8 + kk) * 512 + l * 8] = o;
    }
  }
}

// ---------------- kernel: MFMA bf16 screen (wave-per-chunk-quarter) ---------
// 1313 blocks; block = 4 waves. Each wave owns ALL 64 labels (A-frags: 4 sets
// x 8 regs) and processes groups g = w, w+4, ... straight from global packed
// (coalesced 1KB bursts, 2-deep bA/bB register pipeline). Zero LDS-B traffic,
// zero main-loop barriers. Keys approximate (bf16); exact re-rank finalizes.

__global__ __launch_bounds__(256) void k_screen_mfma(
    const unsigned short* __restrict__ lblbf,
    const unsigned short* __restrict__ packed,
    const float* __restrict__ pnorm,
    float* __restrict__ part_s, int* __restrict__ part_i) {
  __shared__ float pn_lds[PBLK4];          // 3.97 KB
  __shared__ float stv[64][4][KPS4];       // 9.2 KB
  __shared__ int   sti[64][4][KPS4];       // 9.2 KB
  const int tid = threadIdx.x;
  const int w = tid >> 6, l = tid & 63;
  const int col = l & 15, kg = l >> 4;
  const int lgrp = blockIdx.x % 13;
  const int chunk = blockIdx.x / 13;
  const int lab0 = lgrp * 64;
  const int p0 = chunk * PBLK4;
  const int grp0 = p0 >> 4;
  const int ngrp = min(PBLK4 / 16, (NPATCH - p0 + 15) >> 4);

  for (int e = tid; e < PBLK4; e += 256) {
    int p = p0 + e;
    pn_lds[e] = (p < NPATCH) ? pnorm[p] : INFINITY;
  }

  bf16x8 a0[8], a1[8], a2[8], a3[8];
#pragma unroll
  for (int kk = 0; kk < 8; ++kk) {
    size_t off = (size_t)kk * 32 + kg * 8;
    a0[kk] = *(const bf16x8*)&lblbf[(size_t)(lab0 + 0 + col) * CDIM + off];
    a1[kk] = *(const bf16x8*)&lblbf[(size_t)(lab0 + 16 + col) * CDIM + off];
    a2[kk] = *(const bf16x8*)&lblbf[(size_t)(lab0 + 32 + col) * CDIM + off];
    a3[kk] = *(const bf16x8*)&lblbf[(size_t)(lab0 + 48 + col) * CDIM + off];
  }

  float lv[4][SL4]; int li[4][SL4];
#pragma unroll
  for (int s = 0; s < 4; ++s)
#pragma unroll
    for (int j = 0; j < SL4; ++j) { lv[s][j] = INFINITY; li[s][j] = 0x7fffffff; }

  __syncthreads();  // pn_lds ready (only barrier before end merge)

  auto loadB = [&](int g, bf16x8* bb) {
    int gg = grp0 + g;
    if (gg > NGRPTOT - 1) gg = NGRPTOT - 1;
    const unsigned short* pr = packed + (size_t)gg * 4096 + l * 8;
#pragma unroll
    for (int kk = 0; kk < 8; ++kk) bb[kk] = *(const bf16x8*)&pr[kk * 512];
  };

#define COMPSET(aa, s_)                                                       \
  {                                                                           \
    f32x4 ac0 = {0.f, 0.f, 0.f, 0.f}, ac1 = {0.f, 0.f, 0.f, 0.f};            \
    _Pragma("unroll") for (int kk = 0; kk < 4; ++kk) {                        \
      ac0 = __builtin_amdgcn_mfma_f32_16x16x32_bf16(bb[2 * kk], aa[2 * kk],   \
                                                    ac0, 0, 0, 0);            \
      ac1 = __builtin_amdgcn_mfma_f32_16x16x32_bf16(bb[2 * kk + 1],           \
                                                    aa[2 * kk + 1], ac1,      \
                                                    0, 0, 0);                 \
    }                                                                         \
    float k0 = fmaf(-2.f, ac0[0] + ac1[0], pn0);                              \
    float k1 = fmaf(-2.f, ac0[1] + ac1[1], pn1);                              \
    float k2 = fmaf(-2.f, ac0[2] + ac1[2], pn2);                              \
    float k3 = fmaf(-2.f, ac0[3] + ac1[3], pn3);                              \
    if (fminf(fminf(k0, k1), fminf(k2, k3)) < lv[s_][SL4 - 1]) {              \
      tk_fast<SL4>(lv[s_], li[s_], k0, pb + 0);                               \
      tk_fast<SL4>(lv[s_], li[s_], k1, pb + 1);                               \
      tk_fast<SL4>(lv[s_], li[s_], k2, pb + 2);                               \
      tk_fast<SL4>(lv[s_], li[s_], k3, pb + 3);                               \
    }                                                                         \
  }

#define COMPUTE(g, bbuf)                                                      \
  {                                                                           \
    const bf16x8* bb = (bbuf);                                                \
    const int pib = (g) * 16 + kg * 4;                                        \
    const float pn0 = pn_lds[pib + 0], pn1 = pn_lds[pib + 1];                 \
    const float pn2 = pn_lds[pib + 2], pn3 = pn_lds[pib + 3];                 \
    const int pb = p0 + pib;                                                  \
    COMPSET(a0, 0); COMPSET(a1, 1); COMPSET(a2, 2); COMPSET(a3, 3);           \
  }

  const int nit = (ngrp > w) ? ((ngrp - w + 3) >> 2) : 0;  // groups this wave
  bf16x8 bA[8], bB[8];
  if (nit > 0) loadB(w, bA);
  for (int t = 0; t < nit; t += 2) {
    int g0 = w + 4 * t, g1 = g0 + 4;
    bool has1 = (t + 1 < nit);
    if (has1) loadB(g1, bB);
    COMPUTE(g0, bA);
    if (t + 2 < nit) loadB(g0 + 8, bA);
    if (has1) COMPUTE(g1, bB);
  }
#undef COMPUTE
#undef COMPSET

  // per-set in-wave merge (lanes kg=0..3 share col) -> per-(label,wave) top-9
#pragma unroll
  for (int s = 0; s < 4; ++s) {
    float v9[KPS4]; int i9[KPS4];
#pragma unroll
    for (int j = 0; j < KPS4; ++j) {
      v9[j] = (j < SL4) ? lv[s][j] : INFINITY;
      i9[j] = (j < SL4) ? li[s][j] : 0x7fffffff;
    }
#pragma unroll
    for (int j = 0; j < SL4; ++j) {
      float rv = __shfl_xor(lv[s][j], 16);
      int ri = __shfl_xor(li[s][j], 16);
      tk_fast<KPS4>(v9, i9, rv, ri);
    }
    {
      float tv[KPS4]; int ti[KPS4];
#pragma unroll
      for (int j = 0; j < KPS4; ++j) { tv[j] = v9[j]; ti[j] = i9[j]; }
#pragma unroll
      for (int j = 0; j < KPS4; ++j) {
        float rv = __shfl_xor(tv[j], 32);
        int ri = __shfl_xor(ti[j], 32);
        tk_fast<KPS4>(v9, i9, rv, ri);
      }
    }
    if (kg == 0) {
#pragma unroll
      for (int j = 0; j < KPS4; ++j) {
        stv[s * 16 + col][w][j] = v9[j];
        sti[s * 16 + col][w][j] = i9[j];
      }
    }
  }
  __syncthreads();
  // cross-wave merge: 4 waves x 9 -> per-(label,chunk) top-9
  if (tid < 64) {
    float v[KPS4]; int ii[KPS4];
#pragma unroll
    for (int j = 0; j < KPS4; ++j) { v[j] = INFINITY; ii[j] = 0x7fffffff; }
    for (int wv = 0; wv < 4; ++wv)
#pragma unroll
      for (int j = 0; j < KPS4; ++j)
        tk_insert<KPS4>(v, ii, stv[tid][wv][j], sti[tid][wv][j]);
    size_t base = ((size_t)(lab0 + tid) * NCH4 + chunk) * KPS4;
#pragma unroll
    for (int j = 0; j < KPS4; ++j) { part_s[base + j] = v[j]; part_i[base + j] = ii[j]; }
  }
}

// ---------------- tail device bodies (bit-proven, pointer-param form) -------

__device__ __forceinline__ double dev_block_sum(double x, double* red) {
#pragma unroll
  for (int m = 32; m >= 1; m >>= 1) x += __shfl_xor(x, m);
  int wid = threadIdx.x >> 6, lane = threadIdx.x & 63;
  if (lane == 0) red[wid] = x;
  __syncthreads();
  double s = red[0] + red[1] + red[2] + red[3];
  __syncthreads();
  return s;
}

__device__ void dev_level_out2(float* xs, double* red, int row,
                               const float* emb, const float* c1,
                               const float* c2, const float* c3, int nseg,
                               const float* W, const float* bias,
                               const float* gamma, const float* beta,
                               float* out, float* onorm) {
  const int ch = threadIdx.x;
  float e = emb[(size_t)row * CDIM + ch];
  xs[ch] = e;
  if (nseg > 1) xs[CDIM + ch] = c1[(size_t)row * CDIM + ch];
  if (nseg > 2) xs[2 * CDIM + ch] = c2[(size_t)row * CDIM + ch];
  if (nseg > 3) xs[3 * CDIM + ch] = c3[(size_t)row * CDIM + ch];
  __syncthreads();
  const int F = nseg * CDIM;
  double ys[8];
#pragma unroll
  for (int m = 0; m < 8; ++m) ys[m] = 0.0;
  for (int j = 0; j < F; j += 8)
#pragma unroll
    for (int m = 0; m < 8; ++m)
      ys[m] += (double)xs[j + m] * (double)W[(size_t)(j + m) * CDIM + ch];
  double y = (double)e + (double)bias[ch] +
             (((ys[0] + ys[1]) + (ys[2] + ys[3])) +
              ((ys[4] + ys[5]) + (ys[6] + ys[7])));
  double mu = dev_block_sum(y, red) * (1.0 / 256.0);
  double d = y - mu;
  double var = dev_block_sum(d * d, red) * (1.0 / 256.0);
  float o = (float)(d / sqrt(var + 1e-5) * (double)gamma[ch] + (double)beta[ch]);
  out[(size_t)row * CDIM + ch] = o;
  if (onorm != nullptr) {
    __syncthreads();
    xs[ch] = o;
    __syncthreads();
    if (ch < 16) {
      int h = (ch >> 3) & 1, i = ch & 7;
      const float* a = &xs[h * 128];
      float x = a[i];
      float acc = __fmul_rn(x, x);
#pragma unroll
      for (int j = 1; j < 16; ++j) {
        float yv = a[j * 8 + i];
        acc = __fadd_rn(acc, __fmul_rn(yv, yv));
      }
      float t = __fadd_rn(acc, __shfl_xor(acc, 1));
      t = __fadd_rn(t, __shfl_xor(t, 2));
      t = __fadd_rn(t, __shfl_xor(t, 4));
      float ot = __shfl_xor(t, 8);
      if (h == 0 && i == 0) onorm[row] = __fadd_rn(t, ot);
    }
  }
}

__device__ void dev_small_agg2(float* lsh, float (*st)[257], float* skey,
                               int* nb, int row, const float* lbl_rows,
                               const float* tgt, float lns, const float* tnorm,
                               int M, int k, float* ctx) {
  const int tid = threadIdx.x;
  lsh[tid] = lbl_rows[(size_t)row * CDIM + tid];
  float key = INFINITY;
  const int nbatch = (M + 63) / 64;
#pragma unroll 1
  for (int b = 0; b < nbatch; ++b) {
    __syncthreads();
    for (int idx = tid; idx < 64 * 64; idx += 256) {
      int r = idx >> 6, j = idx & 63;
      int gr = b * 64 + r;
      if (gr < M) {
        float4 v = *(const float4*)&tgt[(size_t)gr * CDIM + j * 4];
        st[r][j * 4 + 0] = v.x; st[r][j * 4 + 1] = v.y;
        st[r][j * 4 + 2] = v.z; st[r][j * 4 + 3] = v.w;
      }
    }
    __syncthreads();
    int myr = tid - b * 64;
    if (myr >= 0 && myr < 64 && tid < M) {
      const float* a = st[myr];
      float dot = 0.f;
      for (int c = 0; c < CDIM; ++c) dot = fmaf(lsh[c], a[c], dot);
      key = np_key(lns, dot, tnorm[tid]);
    }
  }
  skey[tid] = key;
  __syncthreads();
  {
    int rank = 0;
    for (int j = 0; j < M; ++j) {
      float kj = skey[j];
      rank += (kj < key || (kj == key && j < tid)) ? 1 : 0;
    }
    if (tid < M && rank < k) nb[rank] = tid;
  }
  __syncthreads();
  float mx = -INFINITY;
  for (int t = 0; t < k; ++t) mx = fmaxf(mx, tgt[(size_t)nb[t] * CDIM + tid]);
  ctx[(size_t)row * CDIM + tid] = mx - lsh[tid];
}

struct TailSmem {
  float lsh[CDIM];
  union {
    struct { float st[64][257]; float skey[256]; int nb[4]; } agg;
    struct { float xs[4 * CDIM]; } lo;
  } u;
};

// ---------------- kernel: merge + exact re-rank + max-agg (+mood LN) --------

__global__ void k_merge_mfma(const float* __restrict__ part_s,
                             const int* __restrict__ part_i,
                             const float* __restrict__ patch,
                             const float* __restrict__ lbl,
                             const float* __restrict__ pnorm,
                             const float* __restrict__ lnorm,
                             float* __restrict__ ctx,
                             const float* __restrict__ mood_emb,
                             const float* __restrict__ Wm_w,
                             const float* __restrict__ Wm_b,
                             const float* __restrict__ lnm_g,
                             const float* __restrict__ lnm_b,
                             float* __restrict__ out,
                             float* __restrict__ onorm_m) {
  const int lab = blockIdx.x;
  const int tid = threadIdx.x;
  __shared__ float lsh[CDIM];
  __shared__ float st[64][257];    // 65.8 KB staging (reused as xs for mood LN)
  __shared__ float sv[64 * 12];
  __shared__ int   si[64 * 12];
  __shared__ int   cidx[NCAND];
  __shared__ float ckey[NCAND];
  __shared__ int   nb[KTOP];
  __shared__ double redm[4];

  lsh[tid] = lbl[(size_t)lab * CDIM + tid];
  const int total = NCH4 * KPS4;  // 909
  if (tid < 64) {
    float v[12]; int ii[12];
#pragma unroll
    for (int j = 0; j < 12; ++j) { v[j] = INFINITY; ii[j] = 0x7fffffff; }
    for (int e = tid; e < total; e += 64)
      tk_insert<12>(v, ii, part_s[(size_t)lab * total + e],
                    part_i[(size_t)lab * total + e]);
#pragma unroll
    for (int j = 0; j < 12; ++j) { sv[tid * 12 + j] = v[j]; si[tid * 12 + j] = ii[j]; }
  }
  __syncthreads();
  if (tid < 16) {
    float v[12]; int ii[12];
#pragma unroll
    for (int j = 0; j < 12; ++j) { v[j] = INFINITY; ii[j] = 0x7fffffff; }
    for (int e = 0; e < 48; ++e)
      tk_insert<12>(v, ii, sv[tid * 48 + e], si[tid * 48 + e]);
#pragma unroll
    for (int j = 0; j < 12; ++j) cidx[tid * 12 + j] = ii[j];
  }
  __syncthreads();
  float key = INFINITY;
  const float ln = lnorm[lab];
#pragma unroll 1
  for (int b = 0; b < NCAND / 64; ++b) {
    for (int idx = tid; idx < 64 * 64; idx += 256) {
      int r = idx >> 6, j = idx & 63;
      int c = cidx[b * 64 + r];
      if (c != 0x7fffffff) {
        float4 v = *(const float4*)&patch[(size_t)c * CDIM + j * 4];
        st[r][j * 4 + 0] = v.x; st[r][j * 4 + 1] = v.y;
        st[r][j * 4 + 2] = v.z; st[r][j * 4 + 3] = v.w;
      }
    }
    __syncthreads();
    int myr = tid - b * 64;
    if (myr >= 0 && myr < 64) {
      int c = cidx[tid];
      if (c != 0x7fffffff) {
        const float* a = st[myr];
        float dot = 0.f;
        for (int k = 0; k < CDIM; ++k) dot = fmaf(lsh[k], a[k], dot);
        key = np_key(ln, dot, pnorm[c]);
      }
    }
    __syncthreads();
  }
  if (tid < NCAND) ckey[tid] = key;
  __syncthreads();
  if (tid < NCAND) {
    float myk = ckey[tid]; int myc = cidx[tid];
    int rank = 0;
    for (int j = 0; j < NCAND; ++j) {
      float kj = ckey[j]; int cj = cidx[j];
      rank += (kj < myk || (kj == myk && cj < myc)) ? 1 : 0;
    }
    if (myc != 0x7fffffff && rank < KTOP) nb[rank] = myc;
  }
  __syncthreads();
  float mx = -INFINITY;
#pragma unroll
  for (int j = 0; j < KTOP; ++j)
    mx = fmaxf(mx, patch[(size_t)nb[j] * CDIM + tid]);
  ctx[(size_t)lab * CDIM + tid] = mx - lsh[tid];

  // fused mood level_out for lab < 64 (row-aligned; reads own writes)
  if (lab < NMOOD) {
    __syncthreads();
    dev_level_out2(&st[0][0], redm, lab, mood_emb, ctx, nullptr, nullptr, 2,
                   Wm_w, Wm_b, lnm_g, lnm_b, out, onorm_m);
  }
}

// ---------------- kernel: genre = small_agg + level_out (fused per row) -----

__global__ void k_genre(const float* __restrict__ genre_emb,
                        const float* __restrict__ out_mood,
                        const float* __restrict__ lnorm,
                        const float* __restrict__ onorm_m,
                        const float* __restrict__ ctx_all,
                        const float* __restrict__ Wg_w,
                        const float* __restrict__ Wg_b,
                        const float* __restrict__ lng_g,
                        const float* __restrict__ lng_b,
                        float* __restrict__ ctx_gm, float* __restrict__ out,
                        float* __restrict__ onorm_g) {
  __shared__ TailSmem sm;
  __shared__ double red2[4];
  const int b = blockIdx.x;
  dev_small_agg2(sm.lsh, sm.u.agg.st, sm.u.agg.skey, sm.u.agg.nb, b, genre_emb,
                 out_mood, lnorm[NMOOD + b], onorm_m, NMOOD, 4, ctx_gm);
  __syncthreads();
  dev_level_out2(sm.u.lo.xs, red2, b, genre_emb, ctx_all + NMOOD * CDIM,
                 ctx_gm, nullptr, 3, Wg_w, Wg_b, lng_g, lng_b,
                 out + NMOOD * CDIM, onorm_g);
}

// ---------------- kernel: sub = agg + agg + level_out (fused per row) -------

__global__ void k_sub(const float* __restrict__ sub_emb,
                      const float* __restrict__ out_mood,
                      const float* __restrict__ out_genre,
                      const float* __restrict__ lnorm,
                      const float* __restrict__ onorm_m,
                      const float* __restrict__ onorm_g,
                      const float* __restrict__ ctx_all,
                      const float* __restrict__ Ws_w,
                      const float* __restrict__ Ws_b,
                      const float* __restrict__ lns_g,
                      const float* __restrict__ lns_b,
                      float* __restrict__ ctx_sm, float* __restrict__ ctx_sg,
                      float* __restrict__ out) {
  __shared__ TailSmem sm;
  __shared__ double red2[4];
  const int b = blockIdx.x;
  const float lns = lnorm[NMOOD + NGENRE + b];
  dev_small_agg2(sm.lsh, sm.u.agg.st, sm.u.agg.skey, sm.u.agg.nb, b, sub_emb,
                 out_mood, lns, onorm_m, NMOOD, 3, ctx_sm);
  __syncthreads();
  dev_small_agg2(sm.lsh, sm.u.agg.st, sm.u.agg.skey, sm.u.agg.nb, b, sub_emb,
                 out_genre, lns, onorm_g, NGENRE, 4, ctx_sg);
  __syncthreads();
  dev_level_out2(sm.u.lo.xs, red2, b, sub_emb,
                 ctx_all + (NMOOD + NGENRE) * CDIM, ctx_sm, ctx_sg, 4,
                 Ws_w, Ws_b, lns_g, lns_b, out + (NMOOD + NGENRE) * CDIM,
                 nullptr);
}

// ---------------- FALLBACK path kernels (R4 screen + standalone tail) -------

__global__ void k_concat_labels(const float* __restrict__ mood,
                                const float* __restrict__ genre,
                                const float* __restrict__ sub,
                                float* __restrict__ lbl) {
  int i = blockIdx.x * 256 + threadIdx.x;
  if (i < NMOOD * CDIM) lbl[i] = mood[i];
  else if (i < (NMOOD + NGENRE) * CDIM) lbl[i] = genre[i - NMOOD * CDIM];
  else lbl[i] = sub[i - (NMOOD + NGENRE) * CDIM];
}

__global__ void k_norms_np(const float* __restrict__ m, int n,
                           float* __restrict__ out) {
  int i = blockIdx.x * blockDim.x + threadIdx.x;
  int stride = gridDim.x * blockDim.x;
  for (; i < n; i += stride) out[i] = np_sq256(m + (size_t)i * CDIM);
}

__global__ void k_screen_f32(const float* __restrict__ lbl,
                             const float* __restrict__ patch,
                             const float* __restrict__ pnorm,
                             const float* __restrict__ lnorm,
                             float* __restrict__ part_s,
                             int* __restrict__ part_i) {
  __shared__ float Asm[KC][BLK];
  __shared__ float Bsm[KC][BLK];
  __shared__ float sc[BLK][BLK + 1];
  const int tid = threadIdx.x;
  const int tr = tid >> 4, tc = tid & 15;
  const int lbase = blockIdx.y * BLK;
  const int chunk = blockIdx.x;
  const int p0 = chunk * CHUNK;
  const int p1 = (p0 + CHUNK < NPATCH) ? p0 + CHUNK : NPATCH;

  float tv[KP]; int ti[KP];
#pragma unroll
  for (int j = 0; j < KP; ++j) { tv[j] = INFINITY; ti[j] = 0x7fffffff; }
  const float ln = (tid < BLK) ? lnorm[lbase + tid] : 0.f;

  const int sl = tid >> 2;
  const int skq = (tid & 3) * 4;

  for (int pt = p0; pt < p1; pt += BLK) {
    float acc[4][4];
#pragma unroll
    for (int a = 0; a < 4; ++a)
#pragma unroll
      for (int b = 0; b < 4; ++b) acc[a][b] = 0.f;

    for (int kc = 0; kc < CDIM; kc += KC) {
      __syncthreads();
      {
        const float* arow = &lbl[(size_t)(lbase + sl) * CDIM + kc];
        float4 va0 = *(const float4*)(arow + skq);
        float4 va1 = *(const float4*)(arow + 16 + skq);
        Asm[skq + 0][sl] = va0.x; Asm[skq + 1][sl] = va0.y;
        Asm[skq + 2][sl] = va0.z; Asm[skq + 3][sl] = va0.w;
        Asm[16 + skq + 0][sl] = va1.x; Asm[16 + skq + 1][sl] = va1.y;
        Asm[16 + skq + 2][sl] = va1.z; Asm[16 + skq + 3][sl] = va1.w;
        int p = pt + sl;
        float4 vb0 = make_float4(0.f, 0.f, 0.f, 0.f), vb1 = vb0;
        if (p < p1) {
          const float* brow = &patch[(size_t)p * CDIM + kc];
          vb0 = *(const float4*)(brow + skq);
          vb1 = *(const float4*)(brow + 16 + skq);
        }
        Bsm[skq + 0][sl] = vb0.x; Bsm[skq + 1][sl] = vb0.y;
        Bsm[skq + 2][sl] = vb0.z; Bsm[skq + 3][sl] = vb0.w;
        Bsm[16 + skq + 0][sl] = vb1.x; Bsm[16 + skq + 1][sl] = vb1.y;
        Bsm[16 + skq + 2][sl] = vb1.z; Bsm[16 + skq + 3][sl] = vb1.w;
      }
      __syncthreads();
#pragma unroll
      for (int k = 0; k < KC; ++k) {
        float4 a4 = *(const float4*)&Asm[k][tr * 4];
        float4 b4 = *(const float4*)&Bsm[k][tc * 4];
        const float av[4] = {a4.x, a4.y, a4.z, a4.w};
        const float bv[4] = {b4.x, b4.y, b4.z, b4.w};
#pragma unroll
        for (int a = 0; a < 4; ++a)
#pragma unroll
          for (int b = 0; b < 4; ++b) acc[a][b] = fmaf(av[a], bv[b], acc[a][b]);
      }
    }
#pragma unroll
    for (int a = 0; a < 4; ++a)
#pragma unroll
      for (int b = 0; b < 4; ++b) sc[tr * 4 + a][tc * 4 + b] = acc[a][b];
    __syncthreads();
    if (tid < BLK) {
      for (int c = 0; c < BLK; ++c) {
        int p = pt + c;
        if (p < p1) tk_insert<KP>(tv, ti, np_key(ln, sc[tid][c], pnorm[p]), p);
      }
    }
  }

  if (tid < BLK) {
    int lab = lbase + tid;
    size_t base = ((size_t)lab * NCHUNK + chunk) * KP;
#pragma unroll
    for (int j = 0; j < KP; ++j) { part_s[base + j] = tv[j]; part_i[base + j] = ti[j]; }
  }
}

__global__ void k_merge_f32(const float* __restrict__ part_s,
                            const int* __restrict__ part_i,
                            const float* __restrict__ patch,
                            const float* __restrict__ lbl,
                            float* __restrict__ ctx) {
  const int lab = blockIdx.x;
  const int tid = threadIdx.x;
  __shared__ float cv[16][KP];
  __shared__ int ci[16][KP];
  __shared__ int nb[KTOP];

  const int total = NCHUNK * KP;
  if (tid < 16) {
    float v[KP]; int ii[KP];
#pragma unroll
    for (int j = 0; j < KP; ++j) { v[j] = INFINITY; ii[j] = 0x7fffffff; }
    for (int e = tid; e < total; e += 16)
      tk_insert<KP>(v, ii, part_s[(size_t)lab * total + e],
                    part_i[(size_t)lab * total + e]);
#pragma unroll
    for (int j = 0; j < KP; ++j) { cv[tid][j] = v[j]; ci[tid][j] = ii[j]; }
  }
  __syncthreads();
  if (tid == 0) {
    float v[KP]; int ii[KP];
#pragma unroll
    for (int j = 0; j < KP; ++j) { v[j] = INFINITY; ii[j] = 0x7fffffff; }
    for (int t = 0; t < 16; ++t)
      for (int j = 0; j < KP; ++j) tk_insert<KP>(v, ii, cv[t][j], ci[t][j]);
#pragma unroll
    for (int j = 0; j < KTOP; ++j) nb[j] = ii[j];
  }
  __syncthreads();
  float l = lbl[(size_t)lab * CDIM + tid];
  float mx = -INFINITY;
#pragma unroll
  for (int j = 0; j < KTOP; ++j)
    mx = fmaxf(mx, patch[(size_t)nb[j] * CDIM + tid]);
  ctx[(size_t)lab * CDIM + tid] = mx - l;
}

__global__ void k_small_agg(const float* __restrict__ lbl_rows,
                            const float* __restrict__ tgt,
                            const float* __restrict__ lnormb,
                            const float* __restrict__ tnorm,
                            int M, int k, float* __restrict__ ctx) {
  __shared__ TailSmem sm;
  dev_small_agg2(sm.lsh, sm.u.agg.st, sm.u.agg.skey, sm.u.agg.nb, blockIdx.x,
                 lbl_rows, tgt, lnormb[blockIdx.x], tnorm, M, k, ctx);
}

__global__ void k_level_out(const float* __restrict__ emb,
                            const float* __restrict__ c1,
                            const float* __restrict__ c2,
                            const float* __restrict__ c3, int nseg,
                            const float* __restrict__ W,
                            const float* __restrict__ bias,
                            const float* __restrict__ gamma,
                            const float* __restrict__ beta,
                            float* __restrict__ out,
                            float* __restrict__ onorm) {
  __shared__ TailSmem sm;
  __shared__ double red2[4];
  dev_level_out2(sm.u.lo.xs, red2, blockIdx.x, emb, c1, c2, c3, nseg, W, bias,
                 gamma, beta, out, onorm);
}

// ---------------- launch ----------------------------------------------------

extern "C" void kernel_launch(void* const* d_in, const int* in_sizes, int n_in,
                              void* d_out, int out_size, void* d_ws, size_t ws_size,
                              hipStream_t stream) {
  const float* patch     = (const float*)d_in[0];
  const float* mood_emb  = (const float*)d_in[1];
  const float* genre_emb = (const float*)d_in[2];
  const float* sub_emb   = (const float*)d_in[3];
  const float* Wm_w = (const float*)d_in[4];
  const float* Wm_b = (const float*)d_in[5];
  const float* Wg_w = (const float*)d_in[6];
  const float* Wg_b = (const float*)d_in[7];
  const float* Ws_w = (const float*)d_in[8];
  const float* Ws_b = (const float*)d_in[9];
  const float* lnm_g = (const float*)d_in[10];
  const float* lnm_b = (const float*)d_in[11];
  const float* lng_g = (const float*)d_in[12];
  const float* lng_b = (const float*)d_in[13];
  const float* lns_g = (const float*)d_in[14];
  const float* lns_b = (const float*)d_in[15];
  float* out = (float*)d_out;
  float* ws = (float*)d_ws;

  const size_t REQ = 15274432ull * 4ull;  // ~61.1 MB (proven fits, R10-R15)

  if (ws_size >= REQ) {
    // ---- MFMA path layout (unchanged) ----
    float* lbl     = ws;                     // 212992
    float* pnorm   = lbl + NLBL * CDIM;      // 100352
    float* lnorm   = pnorm + 100352;         // 1024
    float* ctx_all = lnorm + 1024;           // 212992
    float* ctx_gm  = ctx_all + NLBL * CDIM;  // 65536
    float* ctx_sm  = ctx_gm + NGENRE * CDIM; // 131072
    float* ctx_sg  = ctx_sm + NSUB * CDIM;   // 131072
    float* part_s  = ctx_sg + NSUB * CDIM;   // 756288
    int*   part_i  = (int*)(part_s + (size_t)NLBL * NCH4 * KPS4);
    unsigned short* packed = (unsigned short*)(part_i + (size_t)NLBL * NCH4 * KPS4);
    unsigned short* lblbf  = packed + (size_t)NPATCH * CDIM;
    float* onorm_m = (float*)(lblbf + (size_t)NLBL * CDIM);  // 64
    float* onorm_g = onorm_m + NMOOD;                        // 256

    k_prep3<<<2048, 256, 0, stream>>>(patch, mood_emb, genre_emb, sub_emb,
                                      packed, pnorm, lbl, lblbf, lnorm);
    k_screen_mfma<<<13 * NCH4, 256, 0, stream>>>(lblbf, packed, pnorm,
                                                 part_s, part_i);
    k_merge_mfma<<<NLBL, 256, 0, stream>>>(part_s, part_i, patch, lbl, pnorm,
                                           lnorm, ctx_all, mood_emb, Wm_w,
                                           Wm_b, lnm_g, lnm_b, out, onorm_m);
    k_genre<<<NGENRE, 256, 0, stream>>>(genre_emb, out, lnorm, onorm_m,
                                        ctx_all, Wg_w, Wg_b, lng_g, lng_b,
                                        ctx_gm, out, onorm_g);
    k_sub<<<NSUB, 256, 0, stream>>>(sub_emb, out, out + NMOOD * CDIM, lnorm,
                                    onorm_m, onorm_g, ctx_all, Ws_w, Ws_b,
                                    lns_g, lns_b, ctx_sm, ctx_sg, out);
  } else {
    // ---- R4 fallback layout ----
    float* lbl    = ws;
    float* pnorm  = lbl + NLBL * CDIM;
    float* lnorm  = pnorm + 100352;
    float* part_s = lnorm + 1024;
    int*   part_i = (int*)(part_s + NLBL * NCHUNK * KP);
    float* ctx_all = part_s + 2 * NLBL * NCHUNK * KP;
    float* ctx_gm  = ctx_all + NLBL * CDIM;
    float* ctx_sm  = ctx_gm + NGENRE * CDIM;
    float* ctx_sg  = ctx_sm + NSUB * CDIM;
    float* onorm_m = ctx_sg + NSUB * CDIM;
    float* onorm_g = onorm_m + NMOOD;

    k_concat_labels<<<NLBL, 256, 0, stream>>>(mood_emb, genre_emb, sub_emb, lbl);
    k_norms_np<<<512, 256, 0, stream>>>(patch, NPATCH, pnorm);
    k_norms_np<<<4, 256, 0, stream>>>(lbl, NLBL, lnorm);
    dim3 gscr(NCHUNK, NLBL / BLK);
    k_screen_f32<<<gscr, 256, 0, stream>>>(lbl, patch, pnorm, lnorm, part_s, part_i);
    k_merge_f32<<<NLBL, 256, 0, stream>>>(part_s, part_i, patch, lbl, ctx_all);
    k_level_out<<<NMOOD, 256, 0, stream>>>(mood_emb, ctx_all, nullptr, nullptr, 2,
                                           Wm_w, Wm_b, lnm_g, lnm_b, out, onorm_m);
    k_small_agg<<<NGENRE, 256, 0, stream>>>(genre_emb, out, lnorm + NMOOD,
                                            onorm_m, NMOOD, 4, ctx_gm);
    k_level_out<<<NGENRE, 256, 0, stream>>>(genre_emb, ctx_all + NMOOD * CDIM,
                                            ctx_gm, nullptr, 3, Wg_w, Wg_b,
                                            lng_g, lng_b, out + NMOOD * CDIM,
                                            onorm_g);
    k_small_agg<<<NSUB, 256, 0, stream>>>(sub_emb, out, lnorm + NMOOD + NGENRE,
                                          onorm_m, NMOOD, 3, ctx_sm);
    k_small_agg<<<NSUB, 256, 0, stream>>>(sub_emb, out + NMOOD * CDIM,
                                          lnorm + NMOOD + NGENRE, onorm_g,
                                          NGENRE, 4, ctx_sg);
    k_level_out<<<NSUB, 256, 0, stream>>>(sub_emb,
                                          ctx_all + (NMOOD + NGENRE) * CDIM,
                                          ctx_sm, ctx_sg, 4, Ws_w, Ws_b, lns_g,
                                          lns_b, out + (NMOOD + NGENRE) * CDIM,
                                          nullptr);
  }
}

// Round 18
// 459.205 us; speedup vs baseline: 1.3083x; 1.3083x over previous
//
#include <hip/hip_runtime.h>
#include <math.h>

#define NPATCH 100000
#define CDIM   256
#define NMOOD  64
#define NGENRE 256
#define NSUB   512
#define NLBL   832          // 64+256+512
#define KTOP   9
#define NGRPTOT 6250        // NPATCH/16

// ---- f32 fallback screen constants (R4, known-green) ----
#define NCHUNK 39
#define CHUNK  2624
#define BLK    64
#define KC     32
#define KP     12

// ---- MFMA screen constants ----
#define PBLK4  992          // patches per chunk (62 groups)
#define NCH4   101          // 101*992 = 100192 >= 100000
#define SL4    4            // per-lane list depth
#define KPS4   9            // per-(label,chunk) stored candidates
#define NCAND  192          // merge candidates (64x12 -> 16x12)

typedef __attribute__((ext_vector_type(8))) short bf16x8;
typedef __attribute__((ext_vector_type(8))) unsigned short u16x8;
typedef __attribute__((ext_vector_type(4))) float f32x4;

// ---------------- serial top-k insert (ascending by (val,idx)) --------------

template <int K>
__device__ __forceinline__ void tk_insert(float (&v)[K], int (&ii)[K],
                                          float s, int idx) {
  if (s < v[K - 1] || (s == v[K - 1] && idx < ii[K - 1])) {
    v[K - 1] = s; ii[K - 1] = idx;
#pragma unroll
    for (int t = K - 1; t > 0; --t) {
      bool sw = (v[t] < v[t - 1]) || (v[t] == v[t - 1] && ii[t] < ii[t - 1]);
      if (sw) {
        float fv = v[t]; v[t] = v[t - 1]; v[t - 1] = fv;
        int fi = ii[t]; ii[t] = ii[t - 1]; ii[t - 1] = fi;
      }
    }
  }
}

// fast screen insert: branch-free, NO idx tie-break (ascending-idx processing
// keeps lower idx on equal keys; exact re-rank downstream finalizes order).

template <int K>
__device__ __forceinline__ void tk_fast(float (&v)[K], int (&ii)[K],
                                        float s, int idx) {
  bool ins = s < v[K - 1];
  v[K - 1] = ins ? s : v[K - 1];
  ii[K - 1] = ins ? idx : ii[K - 1];
#pragma unroll
  for (int t = K - 1; t > 0; --t) {
    bool sw = v[t] < v[t - 1];
    float a0 = sw ? v[t] : v[t - 1];
    float a1 = sw ? v[t - 1] : v[t];
    int b0 = sw ? ii[t] : ii[t - 1];
    int b1 = sw ? ii[t - 1] : ii[t];
    v[t - 1] = a0; v[t] = a1; ii[t - 1] = b0; ii[t] = b1;
  }
}

// ------ numpy-pairwise sum of squares over 256 contiguous floats ------------

__device__ float np_sq256(const float* a) {
  float b0, b1;
  {
    float r[8];
#pragma unroll
    for (int i = 0; i < 8; ++i) { float x = a[i]; r[i] = __fmul_rn(x, x); }
    for (int j = 8; j < 128; j += 8)
#pragma unroll
      for (int i = 0; i < 8; ++i) {
        float x = a[j + i];
        r[i] = __fadd_rn(r[i], __fmul_rn(x, x));
      }
    b0 = __fadd_rn(__fadd_rn(__fadd_rn(r[0], r[1]), __fadd_rn(r[2], r[3])),
                   __fadd_rn(__fadd_rn(r[4], r[5]), __fadd_rn(r[6], r[7])));
  }
  {
    float r[8];
#pragma unroll
    for (int i = 0; i < 8; ++i) { float x = a[128 + i]; r[i] = __fmul_rn(x, x); }
    for (int j = 8; j < 128; j += 8)
#pragma unroll
      for (int i = 0; i < 8; ++i) {
        float x = a[128 + j + i];
        r[i] = __fadd_rn(r[i], __fmul_rn(x, x));
      }
    b1 = __fadd_rn(__fadd_rn(__fadd_rn(r[0], r[1]), __fadd_rn(r[2], r[3])),
                   __fadd_rn(__fadd_rn(r[4], r[5]), __fadd_rn(r[6], r[7])));
  }
  return __fadd_rn(b0, b1);
}

__device__ __forceinline__ float np_key(float ln, float dot, float pn) {
  return __fadd_rn(__fsub_rn(ln, __fmul_rn(2.f, dot)), pn);
}

__device__ __forceinline__ unsigned short f2bf(float x) {
  unsigned u = __float_as_uint(x);
  return (unsigned short)((u + 0x7fffu + ((u >> 16) & 1u)) >> 16);
}

// ---------------- kernel: fused prep (labels + patches) ---------------------

__global__ __launch_bounds__(256) void k_prep3(
    const float* __restrict__ src, const float* __restrict__ mood,
    const float* __restrict__ genre, const float* __restrict__ sub,
    unsigned short* __restrict__ packed, float* __restrict__ norms,
    float* __restrict__ lbl, unsigned short* __restrict__ lblbf,
    float* __restrict__ lnorm) {
  __shared__ float lds[16][260];
  const int tid = threadIdx.x;
  const int w = tid >> 6, l = tid & 63;
  const int rr = l >> 4;            // norm row within wave quad
  const int h = (l >> 3) & 1;       // 128-half
  const int i = l & 7;              // np accumulator class
  const int col = l & 15, kg = l >> 4;  // pack coords

  if (blockIdx.x < NLBL / 16) {
    const int row = blockIdx.x * 16 + w * 4;
#pragma unroll
    for (int q = 0; q < 4; ++q) {
      int r = row + q;
      const float* srcr = (r < NMOOD) ? &mood[(size_t)r * CDIM]
                        : (r < NMOOD + NGENRE) ? &genre[(size_t)(r - NMOOD) * CDIM]
                        : &sub[(size_t)(r - NMOOD - NGENRE) * CDIM];
      float4 v = *(const float4*)&srcr[l * 4];
      *(float4*)&lbl[(size_t)r * CDIM + l * 4] = v;
      ushort4 o = make_ushort4(f2bf(v.x), f2bf(v.y), f2bf(v.z), f2bf(v.w));
      *(ushort4*)&lblbf[(size_t)r * CDIM + l * 4] = o;
      lds[w * 4 + q][l * 4 + 0] = v.x; lds[w * 4 + q][l * 4 + 1] = v.y;
      lds[w * 4 + q][l * 4 + 2] = v.z; lds[w * 4 + q][l * 4 + 3] = v.w;
    }
    __syncthreads();
    {
      const float* a = &lds[w * 4 + rr][h * 128];
      float x = a[i];
      float acc = __fmul_rn(x, x);
#pragma unroll
      for (int j = 1; j < 16; ++j) {
        float y = a[j * 8 + i];
        acc = __fadd_rn(acc, __fmul_rn(y, y));
      }
      float t = __fadd_rn(acc, __shfl_xor(acc, 1));
      t = __fadd_rn(t, __shfl_xor(t, 2));
      t = __fadd_rn(t, __shfl_xor(t, 4));
      float o = __shfl_xor(t, 8);
      if (h == 0 && i == 0) lnorm[row + rr] = __fadd_rn(t, o);
    }
  }

  for (int gg = blockIdx.x; gg < NGRPTOT; gg += gridDim.x) {
    const int base = gg * 16;       // 6250*16 == 100000: no partial groups
    __syncthreads();                // protect lds reuse
#pragma unroll
    for (int q = 0; q < 4; ++q) {
      int r = base + w * 4 + q;
      float4 v = *(const float4*)&src[(size_t)r * CDIM + l * 4];
      lds[w * 4 + q][l * 4 + 0] = v.x; lds[w * 4 + q][l * 4 + 1] = v.y;
      lds[w * 4 + q][l * 4 + 2] = v.z; lds[w * 4 + q][l * 4 + 3] = v.w;
    }
    __syncthreads();
    {
      const float* a = &lds[w * 4 + rr][h * 128];
      float x = a[i];
      float acc = __fmul_rn(x, x);
#pragma unroll
      for (int j = 1; j < 16; ++j) {
        float y = a[j * 8 + i];
        acc = __fadd_rn(acc, __fmul_rn(y, y));
      }
      float t = __fadd_rn(acc, __shfl_xor(acc, 1));
      t = __fadd_rn(t, __shfl_xor(t, 2));
      t = __fadd_rn(t, __shfl_xor(t, 4));
      float o = __shfl_xor(t, 8);
      if (h == 0 && i == 0) norms[base + w * 4 + rr] = __fadd_rn(t, o);
    }
#pragma unroll
    for (int pass = 0; pass < 2; ++pass) {
      int kk = w + 4 * pass;
      const float* a = &lds[col][kg * 8 + kk * 32];
      u16x8 o;
#pragma unroll
      for (int j = 0; j < 8; ++j) o[j] = f2bf(a[j]);
      *(u16x8*)&packed[((size_t)gg * 8 + kk) * 512 + l * 8] = o;
    }
  }
}

// ---------------- async global->LDS helper ----------------------------------

__device__ __forceinline__ void gload_lds16(const void* g, void* l) {
  __builtin_amdgcn_global_load_lds(
      (const __attribute__((address_space(1))) unsigned int*)g,
      (__attribute__((address_space(3))) unsigned int*)l, 16, 0, 0);
}

// ---------------- kernel: MFMA bf16 screen (R15-proven, VGPR 48) ------------
// Counted-vmcnt LDS pipeline: per group {ds_read bb -> lgkmcnt(0) +
// sched_barrier -> s_barrier -> stage(g+2) -> MFMA/key/insert -> vmcnt(2)
// -> s_barrier}. Measured 183.9 us, occ 31.7%, VALUBusy 70% (R15).

__global__ __launch_bounds__(256) void k_screen_mfma(
    const unsigned short* __restrict__ lblbf,
    const unsigned short* __restrict__ packed,
    const float* __restrict__ pnorm,
    float* __restrict__ part_s, int* __restrict__ part_i) {
  __shared__ float pn_lds[PBLK4];                  // 3.97 KB
  __shared__ __align__(16) char smem[2][8192];     // 16 KB
  const int tid = threadIdx.x;
  const int w = tid >> 6, l = tid & 63;
  const int col = l & 15, kg = l >> 4;
  const int lgrp = blockIdx.x % 13;
  const int chunk = blockIdx.x / 13;
  const int lab0 = lgrp * 64 + w * 16;
  const int p0 = chunk * PBLK4;
  const int grp0 = p0 >> 4;
  const int ngrp = min(PBLK4 / 16, (NPATCH - p0 + 15) >> 4);

  for (int e = tid; e < PBLK4; e += 256) {
    int p = p0 + e;
    pn_lds[e] = (p < NPATCH) ? pnorm[p] : INFINITY;
  }

  bf16x8 a[8];
#pragma unroll
  for (int kk = 0; kk < 8; ++kk)
    a[kk] = *(const bf16x8*)&lblbf[(size_t)(lab0 + col) * CDIM + kk * 32 + kg * 8];

  float lv[SL4]; int li[SL4];
#pragma unroll
  for (int j = 0; j < SL4; ++j) { lv[j] = INFINITY; li[j] = 0x7fffffff; }

  auto stage = [&](int buf, int g) {
    int gg = grp0 + g;
    if (gg > NGRPTOT - 1) gg = NGRPTOT - 1;
    const char* gsrc = (const char*)packed + (size_t)gg * 8192;
    gload_lds16(gsrc + tid * 16, &smem[buf][tid * 16]);
    gload_lds16(gsrc + (tid + 256) * 16, &smem[buf][(tid + 256) * 16]);
  };

  stage(0, 0);
  if (ngrp > 1) stage(1, 1);
  asm volatile("s_waitcnt vmcnt(2)" ::: "memory");
  __builtin_amdgcn_s_barrier();   // pn_lds + stage(0) visible to all waves

  for (int g = 0; g < ngrp; ++g) {
    const int cb = g & 1;
    const char* gb = smem[cb];
    bf16x8 bb[8];
#pragma unroll
    for (int kk = 0; kk < 8; ++kk)
      bb[kk] = *(const bf16x8*)(gb + kk * 1024 + l * 16);
    asm volatile("s_waitcnt lgkmcnt(0)" ::: "memory");
    __builtin_amdgcn_sched_barrier(0);
    __builtin_amdgcn_s_barrier();
    if (g + 2 < ngrp) stage(cb, g + 2);   // overwrite freed buffer
    f32x4 ac0 = {0.f, 0.f, 0.f, 0.f}, ac1 = {0.f, 0.f, 0.f, 0.f};
#pragma unroll
    for (int kk = 0; kk < 4; ++kk) {
      ac0 = __builtin_amdgcn_mfma_f32_16x16x32_bf16(bb[2 * kk], a[2 * kk],
                                                    ac0, 0, 0, 0);
      ac1 = __builtin_amdgcn_mfma_f32_16x16x32_bf16(bb[2 * kk + 1],
                                                    a[2 * kk + 1], ac1,
                                                    0, 0, 0);
    }
    const int pib = g * 16 + kg * 4;
    float k0 = fmaf(-2.f, ac0[0] + ac1[0], pn_lds[pib + 0]);
    float k1 = fmaf(-2.f, ac0[1] + ac1[1], pn_lds[pib + 1]);
    float k2 = fmaf(-2.f, ac0[2] + ac1[2], pn_lds[pib + 2]);
    float k3 = fmaf(-2.f, ac0[3] + ac1[3], pn_lds[pib + 3]);
    if (fminf(fminf(k0, k1), fminf(k2, k3)) < lv[SL4 - 1]) {
      tk_fast<SL4>(lv, li, k0, p0 + pib + 0);
      tk_fast<SL4>(lv, li, k1, p0 + pib + 1);
      tk_fast<SL4>(lv, li, k2, p0 + pib + 2);
      tk_fast<SL4>(lv, li, k3, p0 + pib + 3);
    }
    asm volatile("s_waitcnt vmcnt(2)" ::: "memory");
    __builtin_amdgcn_s_barrier();
  }

  // in-wave merge: lanes {l, l^16, l^32, l^48} share col -> merge 4 lists.
  float v9[KPS4]; int i9[KPS4];
#pragma unroll
  for (int j = 0; j < KPS4; ++j) {
    v9[j] = (j < SL4) ? lv[j] : INFINITY;
    i9[j] = (j < SL4) ? li[j] : 0x7fffffff;
  }
#pragma unroll
  for (int j = 0; j < SL4; ++j) {
    float rv = __shfl_xor(lv[j], 16);
    int ri = __shfl_xor(li[j], 16);
    tk_fast<KPS4>(v9, i9, rv, ri);
  }
  {
    float tv[KPS4]; int ti[KPS4];
#pragma unroll
    for (int j = 0; j < KPS4; ++j) { tv[j] = v9[j]; ti[j] = i9[j]; }
#pragma unroll
    for (int j = 0; j < KPS4; ++j) {
      float rv = __shfl_xor(tv[j], 32);
      int ri = __shfl_xor(ti[j], 32);
      tk_fast<KPS4>(v9, i9, rv, ri);
    }
  }
  if (kg == 0) {
    int lab = lab0 + col;
    size_t base = ((size_t)lab * NCH4 + chunk) * KPS4;
#pragma unroll
    for (int j = 0; j < KPS4; ++j) { part_s[base + j] = v9[j]; part_i[base + j] = i9[j]; }
  }
}

// ---------------- tail device bodies (bit-proven, pointer-param form) -------

__device__ __forceinline__ double dev_block_sum(double x, double* red) {
#pragma unroll
  for (int m = 32; m >= 1; m >>= 1) x += __shfl_xor(x, m);
  int wid = threadIdx.x >> 6, lane = threadIdx.x & 63;
  if (lane == 0) red[wid] = x;
  __syncthreads();
  double s = red[0] + red[1] + red[2] + red[3];
  __syncthreads();
  return s;
}

__device__ void dev_level_out2(float* xs, double* red, int row,
                               const float* emb, const float* c1,
                               const float* c2, const float* c3, int nseg,
                               const float* W, const float* bias,
                               const float* gamma, const float* beta,
                               float* out, float* onorm) {
  const int ch = threadIdx.x;
  float e = emb[(size_t)row * CDIM + ch];
  xs[ch] = e;
  if (nseg > 1) xs[CDIM + ch] = c1[(size_t)row * CDIM + ch];
  if (nseg > 2) xs[2 * CDIM + ch] = c2[(size_t)row * CDIM + ch];
  if (nseg > 3) xs[3 * CDIM + ch] = c3[(size_t)row * CDIM + ch];
  __syncthreads();
  const int F = nseg * CDIM;
  double ys[8];
#pragma unroll
  for (int m = 0; m < 8; ++m) ys[m] = 0.0;
  for (int j = 0; j < F; j += 8)
#pragma unroll
    for (int m = 0; m < 8; ++m)
      ys[m] += (double)xs[j + m] * (double)W[(size_t)(j + m) * CDIM + ch];
  double y = (double)e + (double)bias[ch] +
             (((ys[0] + ys[1]) + (ys[2] + ys[3])) +
              ((ys[4] + ys[5]) + (ys[6] + ys[7])));
  double mu = dev_block_sum(y, red) * (1.0 / 256.0);
  double d = y - mu;
  double var = dev_block_sum(d * d, red) * (1.0 / 256.0);
  float o = (float)(d / sqrt(var + 1e-5) * (double)gamma[ch] + (double)beta[ch]);
  out[(size_t)row * CDIM + ch] = o;
  if (onorm != nullptr) {
    __syncthreads();
    xs[ch] = o;
    __syncthreads();
    if (ch < 16) {
      int h = (ch >> 3) & 1, i = ch & 7;
      const float* a = &xs[h * 128];
      float x = a[i];
      float acc = __fmul_rn(x, x);
#pragma unroll
      for (int j = 1; j < 16; ++j) {
        float yv = a[j * 8 + i];
        acc = __fadd_rn(acc, __fmul_rn(yv, yv));
      }
      float t = __fadd_rn(acc, __shfl_xor(acc, 1));
      t = __fadd_rn(t, __shfl_xor(t, 2));
      t = __fadd_rn(t, __shfl_xor(t, 4));
      float ot = __shfl_xor(t, 8);
      if (h == 0 && i == 0) onorm[row] = __fadd_rn(t, ot);
    }
  }
}

__device__ void dev_small_agg2(float* lsh, float (*st)[257], float* skey,
                               int* nb, int row, const float* lbl_rows,
                               const float* tgt, float lns, const float* tnorm,
                               int M, int k, float* ctx) {
  const int tid = threadIdx.x;
  lsh[tid] = lbl_rows[(size_t)row * CDIM + tid];
  float key = INFINITY;
  const int nbatch = (M + 63) / 64;
#pragma unroll 1
  for (int b = 0; b < nbatch; ++b) {
    __syncthreads();
    for (int idx = tid; idx < 64 * 64; idx += 256) {
      int r = idx >> 6, j = idx & 63;
      int gr = b * 64 + r;
      if (gr < M) {
        float4 v = *(const float4*)&tgt[(size_t)gr * CDIM + j * 4];
        st[r][j * 4 + 0] = v.x; st[r][j * 4 + 1] = v.y;
        st[r][j * 4 + 2] = v.z; st[r][j * 4 + 3] = v.w;
      }
    }
    __syncthreads();
    int myr = tid - b * 64;
    if (myr >= 0 && myr < 64 && tid < M) {
      const float* a = st[myr];
      float dot = 0.f;
      for (int c = 0; c < CDIM; ++c) dot = fmaf(lsh[c], a[c], dot);
      key = np_key(lns, dot, tnorm[tid]);
    }
  }
  skey[tid] = key;
  __syncthreads();
  {
    int rank = 0;
    for (int j = 0; j < M; ++j) {
      float kj = skey[j];
      rank += (kj < key || (kj == key && j < tid)) ? 1 : 0;
    }
    if (tid < M && rank < k) nb[rank] = tid;
  }
  __syncthreads();
  float mx = -INFINITY;
  for (int t = 0; t < k; ++t) mx = fmaxf(mx, tgt[(size_t)nb[t] * CDIM + tid]);
  ctx[(size_t)row * CDIM + tid] = mx - lsh[tid];
}

struct TailSmem {
  float lsh[CDIM];
  union {
    struct { float st[64][257]; float skey[256]; int nb[4]; } agg;
    struct { float xs[4 * CDIM]; } lo;
  } u;
};

// ---------------- kernel: merge + exact re-rank + max-agg (+mood LN) --------

__global__ void k_merge_mfma(const float* __restrict__ part_s,
                             const int* __restrict__ part_i,
                             const float* __restrict__ patch,
                             const float* __restrict__ lbl,
                             const float* __restrict__ pnorm,
                             const float* __restrict__ lnorm,
                             float* __restrict__ ctx,
                             const float* __restrict__ mood_emb,
                             const float* __restrict__ Wm_w,
                             const float* __restrict__ Wm_b,
                             const float* __restrict__ lnm_g,
                             const float* __restrict__ lnm_b,
                             float* __restrict__ out,
                             float* __restrict__ onorm_m) {
  const int lab = blockIdx.x;
  const int tid = threadIdx.x;
  __shared__ float lsh[CDIM];
  __shared__ float st[64][257];    // 65.8 KB staging (reused as xs for mood LN)
  __shared__ float sv[64 * 12];
  __shared__ int   si[64 * 12];
  __shared__ int   cidx[NCAND];
  __shared__ float ckey[NCAND];
  __shared__ int   nb[KTOP];
  __shared__ double redm[4];

  lsh[tid] = lbl[(size_t)lab * CDIM + tid];
  const int total = NCH4 * KPS4;  // 909
  if (tid < 64) {
    float v[12]; int ii[12];
#pragma unroll
    for (int j = 0; j < 12; ++j) { v[j] = INFINITY; ii[j] = 0x7fffffff; }
    for (int e = tid; e < total; e += 64)
      tk_insert<12>(v, ii, part_s[(size_t)lab * total + e],
                    part_i[(size_t)lab * total + e]);
#pragma unroll
    for (int j = 0; j < 12; ++j) { sv[tid * 12 + j] = v[j]; si[tid * 12 + j] = ii[j]; }
  }
  __syncthreads();
  if (tid < 16) {
    float v[12]; int ii[12];
#pragma unroll
    for (int j = 0; j < 12; ++j) { v[j] = INFINITY; ii[j] = 0x7fffffff; }
    for (int e = 0; e < 48; ++e)
      tk_insert<12>(v, ii, sv[tid * 48 + e], si[tid * 48 + e]);
#pragma unroll
    for (int j = 0; j < 12; ++j) cidx[tid * 12 + j] = ii[j];
  }
  __syncthreads();
  float key = INFINITY;
  const float ln = lnorm[lab];
#pragma unroll 1
  for (int b = 0; b < NCAND / 64; ++b) {
    for (int idx = tid; idx < 64 * 64; idx += 256) {
      int r = idx >> 6, j = idx & 63;
      int c = cidx[b * 64 + r];
      if (c != 0x7fffffff) {
        float4 v = *(const float4*)&patch[(size_t)c * CDIM + j * 4];
        st[r][j * 4 + 0] = v.x; st[r][j * 4 + 1] = v.y;
        st[r][j * 4 + 2] = v.z; st[r][j * 4 + 3] = v.w;
      }
    }
    __syncthreads();
    int myr = tid - b * 64;
    if (myr >= 0 && myr < 64) {
      int c = cidx[tid];
      if (c != 0x7fffffff) {
        const float* a = st[myr];
        float dot = 0.f;
        for (int k = 0; k < CDIM; ++k) dot = fmaf(lsh[k], a[k], dot);
        key = np_key(ln, dot, pnorm[c]);
      }
    }
    __syncthreads();
  }
  if (tid < NCAND) ckey[tid] = key;
  __syncthreads();
  if (tid < NCAND) {
    float myk = ckey[tid]; int myc = cidx[tid];
    int rank = 0;
    for (int j = 0; j < NCAND; ++j) {
      float kj = ckey[j]; int cj = cidx[j];
      rank += (kj < myk || (kj == myk && cj < myc)) ? 1 : 0;
    }
    if (myc != 0x7fffffff && rank < KTOP) nb[rank] = myc;
  }
  __syncthreads();
  float mx = -INFINITY;
#pragma unroll
  for (int j = 0; j < KTOP; ++j)
    mx = fmaxf(mx, patch[(size_t)nb[j] * CDIM + tid]);
  ctx[(size_t)lab * CDIM + tid] = mx - lsh[tid];

  // fused mood level_out for lab < 64 (row-aligned; reads own writes)
  if (lab < NMOOD) {
    __syncthreads();
    dev_level_out2(&st[0][0], redm, lab, mood_emb, ctx, nullptr, nullptr, 2,
                   Wm_w, Wm_b, lnm_g, lnm_b, out, onorm_m);
  }
}

// ---------------- kernel: genre = small_agg + level_out (fused per row) -----

__global__ void k_genre(const float* __restrict__ genre_emb,
                        const float* __restrict__ out_mood,
                        const float* __restrict__ lnorm,
                        const float* __restrict__ onorm_m,
                        const float* __restrict__ ctx_all,
                        const float* __restrict__ Wg_w,
                        const float* __restrict__ Wg_b,
                        const float* __restrict__ lng_g,
                        const float* __restrict__ lng_b,
                        float* __restrict__ ctx_gm, float* __restrict__ out,
                        float* __restrict__ onorm_g) {
  __shared__ TailSmem sm;
  __shared__ double red2[4];
  const int b = blockIdx.x;
  dev_small_agg2(sm.lsh, sm.u.agg.st, sm.u.agg.skey, sm.u.agg.nb, b, genre_emb,
                 out_mood, lnorm[NMOOD + b], onorm_m, NMOOD, 4, ctx_gm);
  __syncthreads();
  dev_level_out2(sm.u.lo.xs, red2, b, genre_emb, ctx_all + NMOOD * CDIM,
                 ctx_gm, nullptr, 3, Wg_w, Wg_b, lng_g, lng_b,
                 out + NMOOD * CDIM, onorm_g);
}

// ---------------- kernel: sub = agg + agg + level_out (fused per row) -------

__global__ void k_sub(const float* __restrict__ sub_emb,
                      const float* __restrict__ out_mood,
                      const float* __restrict__ out_genre,
                      const float* __restrict__ lnorm,
                      const float* __restrict__ onorm_m,
                      const float* __restrict__ onorm_g,
                      const float* __restrict__ ctx_all,
                      const float* __restrict__ Ws_w,
                      const float* __restrict__ Ws_b,
                      const float* __restrict__ lns_g,
                      const float* __restrict__ lns_b,
                      float* __restrict__ ctx_sm, float* __restrict__ ctx_sg,
                      float* __restrict__ out) {
  __shared__ TailSmem sm;
  __shared__ double red2[4];
  const int b = blockIdx.x;
  const float lns = lnorm[NMOOD + NGENRE + b];
  dev_small_agg2(sm.lsh, sm.u.agg.st, sm.u.agg.skey, sm.u.agg.nb, b, sub_emb,
                 out_mood, lns, onorm_m, NMOOD, 3, ctx_sm);
  __syncthreads();
  dev_small_agg2(sm.lsh, sm.u.agg.st, sm.u.agg.skey, sm.u.agg.nb, b, sub_emb,
                 out_genre, lns, onorm_g, NGENRE, 4, ctx_sg);
  __syncthreads();
  dev_level_out2(sm.u.lo.xs, red2, b, sub_emb,
                 ctx_all + (NMOOD + NGENRE) * CDIM, ctx_sm, ctx_sg, 4,
                 Ws_w, Ws_b, lns_g, lns_b, out + (NMOOD + NGENRE) * CDIM,
                 nullptr);
}

// ---------------- FALLBACK path kernels (R4 screen + standalone tail) -------

__global__ void k_concat_labels(const float* __restrict__ mood,
                                const float* __restrict__ genre,
                                const float* __restrict__ sub,
                                float* __restrict__ lbl) {
  int i = blockIdx.x * 256 + threadIdx.x;
  if (i < NMOOD * CDIM) lbl[i] = mood[i];
  else if (i < (NMOOD + NGENRE) * CDIM) lbl[i] = genre[i - NMOOD * CDIM];
  else lbl[i] = sub[i - (NMOOD + NGENRE) * CDIM];
}

__global__ void k_norms_np(const float* __restrict__ m, int n,
                           float* __restrict__ out) {
  int i = blockIdx.x * blockDim.x + threadIdx.x;
  int stride = gridDim.x * blockDim.x;
  for (; i < n; i += stride) out[i] = np_sq256(m + (size_t)i * CDIM);
}

__global__ void k_screen_f32(const float* __restrict__ lbl,
                             const float* __restrict__ patch,
                             const float* __restrict__ pnorm,
                             const float* __restrict__ lnorm,
                             float* __restrict__ part_s,
                             int* __restrict__ part_i) {
  __shared__ float Asm[KC][BLK];
  __shared__ float Bsm[KC][BLK];
  __shared__ float sc[BLK][BLK + 1];
  const int tid = threadIdx.x;
  const int tr = tid >> 4, tc = tid & 15;
  const int lbase = blockIdx.y * BLK;
  const int chunk = blockIdx.x;
  const int p0 = chunk * CHUNK;
  const int p1 = (p0 + CHUNK < NPATCH) ? p0 + CHUNK : NPATCH;

  float tv[KP]; int ti[KP];
#pragma unroll
  for (int j = 0; j < KP; ++j) { tv[j] = INFINITY; ti[j] = 0x7fffffff; }
  const float ln = (tid < BLK) ? lnorm[lbase + tid] : 0.f;

  const int sl = tid >> 2;
  const int skq = (tid & 3) * 4;

  for (int pt = p0; pt < p1; pt += BLK) {
    float acc[4][4];
#pragma unroll
    for (int a = 0; a < 4; ++a)
#pragma unroll
      for (int b = 0; b < 4; ++b) acc[a][b] = 0.f;

    for (int kc = 0; kc < CDIM; kc += KC) {
      __syncthreads();
      {
        const float* arow = &lbl[(size_t)(lbase + sl) * CDIM + kc];
        float4 va0 = *(const float4*)(arow + skq);
        float4 va1 = *(const float4*)(arow + 16 + skq);
        Asm[skq + 0][sl] = va0.x; Asm[skq + 1][sl] = va0.y;
        Asm[skq + 2][sl] = va0.z; Asm[skq + 3][sl] = va0.w;
        Asm[16 + skq + 0][sl] = va1.x; Asm[16 + skq + 1][sl] = va1.y;
        Asm[16 + skq + 2][sl] = va1.z; Asm[16 + skq + 3][sl] = va1.w;
        int p = pt + sl;
        float4 vb0 = make_float4(0.f, 0.f, 0.f, 0.f), vb1 = vb0;
        if (p < p1) {
          const float* brow = &patch[(size_t)p * CDIM + kc];
          vb0 = *(const float4*)(brow + skq);
          vb1 = *(const float4*)(brow + 16 + skq);
        }
        Bsm[skq + 0][sl] = vb0.x; Bsm[skq + 1][sl] = vb0.y;
        Bsm[skq + 2][sl] = vb0.z; Bsm[skq + 3][sl] = vb0.w;
        Bsm[16 + skq + 0][sl] = vb1.x; Bsm[16 + skq + 1][sl] = vb1.y;
        Bsm[16 + skq + 2][sl] = vb1.z; Bsm[16 + skq + 3][sl] = vb1.w;
      }
      __syncthreads();
#pragma unroll
      for (int k = 0; k < KC; ++k) {
        float4 a4 = *(const float4*)&Asm[k][tr * 4];
        float4 b4 = *(const float4*)&Bsm[k][tc * 4];
        const float av[4] = {a4.x, a4.y, a4.z, a4.w};
        const float bv[4] = {b4.x, b4.y, b4.z, b4.w};
#pragma unroll
        for (int a = 0; a < 4; ++a)
#pragma unroll
          for (int b = 0; b < 4; ++b) acc[a][b] = fmaf(av[a], bv[b], acc[a][b]);
      }
    }
#pragma unroll
    for (int a = 0; a < 4; ++a)
#pragma unroll
      for (int b = 0; b < 4; ++b) sc[tr * 4 + a][tc * 4 + b] = acc[a][b];
    __syncthreads();
    if (tid < BLK) {
      for (int c = 0; c < BLK; ++c) {
        int p = pt + c;
        if (p < p1) tk_insert<KP>(tv, ti, np_key(ln, sc[tid][c], pnorm[p]), p);
      }
    }
  }

  if (tid < BLK) {
    int lab = lbase + tid;
    size_t base = ((size_t)lab * NCHUNK + chunk) * KP;
#pragma unroll
    for (int j = 0; j < KP; ++j) { part_s[base + j] = tv[j]; part_i[base + j] = ti[j]; }
  }
}

__global__ void k_merge_f32(const float* __restrict__ part_s,
                            const int* __restrict__ part_i,
                            const float* __restrict__ patch,
                            const float* __restrict__ lbl,
                            float* __restrict__ ctx) {
  const int lab = blockIdx.x;
  const int tid = threadIdx.x;
  __shared__ float cv[16][KP];
  __shared__ int ci[16][KP];
  __shared__ int nb[KTOP];

  const int total = NCHUNK * KP;
  if (tid < 16) {
    float v[KP]; int ii[KP];
#pragma unroll
    for (int j = 0; j < KP; ++j) { v[j] = INFINITY; ii[j] = 0x7fffffff; }
    for (int e = tid; e < total; e += 16)
      tk_insert<KP>(v, ii, part_s[(size_t)lab * total + e],
                    part_i[(size_t)lab * total + e]);
#pragma unroll
    for (int j = 0; j < KP; ++j) { cv[tid][j] = v[j]; ci[tid][j] = ii[j]; }
  }
  __syncthreads();
  if (tid == 0) {
    float v[KP]; int ii[KP];
#pragma unroll
    for (int j = 0; j < KP; ++j) { v[j] = INFINITY; ii[j] = 0x7fffffff; }
    for (int t = 0; t < 16; ++t)
      for (int j = 0; j < KP; ++j) tk_insert<KP>(v, ii, cv[t][j], ci[t][j]);
#pragma unroll
    for (int j = 0; j < KTOP; ++j) nb[j] = ii[j];
  }
  __syncthreads();
  float l = lbl[(size_t)lab * CDIM + tid];
  float mx = -INFINITY;
#pragma unroll
  for (int j = 0; j < KTOP; ++j)
    mx = fmaxf(mx, patch[(size_t)nb[j] * CDIM + tid]);
  ctx[(size_t)lab * CDIM + tid] = mx - l;
}

__global__ void k_small_agg(const float* __restrict__ lbl_rows,
                            const float* __restrict__ tgt,
                            const float* __restrict__ lnormb,
                            const float* __restrict__ tnorm,
                            int M, int k, float* __restrict__ ctx) {
  __shared__ TailSmem sm;
  dev_small_agg2(sm.lsh, sm.u.agg.st, sm.u.agg.skey, sm.u.agg.nb, blockIdx.x,
                 lbl_rows, tgt, lnormb[blockIdx.x], tnorm, M, k, ctx);
}

__global__ void k_level_out(const float* __restrict__ emb,
                            const float* __restrict__ c1,
                            const float* __restrict__ c2,
                            const float* __restrict__ c3, int nseg,
                            const float* __restrict__ W,
                            const float* __restrict__ bias,
                            const float* __restrict__ gamma,
                            const float* __restrict__ beta,
                            float* __restrict__ out,
                            float* __restrict__ onorm) {
  __shared__ TailSmem sm;
  __shared__ double red2[4];
  dev_level_out2(sm.u.lo.xs, red2, blockIdx.x, emb, c1, c2, c3, nseg, W, bias,
                 gamma, beta, out, onorm);
}

// ---------------- launch ----------------------------------------------------

extern "C" void kernel_launch(void* const* d_in, const int* in_sizes, int n_in,
                              void* d_out, int out_size, void* d_ws, size_t ws_size,
                              hipStream_t stream) {
  const float* patch     = (const float*)d_in[0];
  const float* mood_emb  = (const float*)d_in[1];
  const float* genre_emb = (const float*)d_in[2];
  const float* sub_emb   = (const float*)d_in[3];
  const float* Wm_w = (const float*)d_in[4];
  const float* Wm_b = (const float*)d_in[5];
  const float* Wg_w = (const float*)d_in[6];
  const float* Wg_b = (const float*)d_in[7];
  const float* Ws_w = (const float*)d_in[8];
  const float* Ws_b = (const float*)d_in[9];
  const float* lnm_g = (const float*)d_in[10];
  const float* lnm_b = (const float*)d_in[11];
  const float* lng_g = (const float*)d_in[12];
  const float* lng_b = (const float*)d_in[13];
  const float* lns_g = (const float*)d_in[14];
  const float* lns_b = (const float*)d_in[15];
  float* out = (float*)d_out;
  float* ws = (float*)d_ws;

  const size_t REQ = 15274432ull * 4ull;  // ~61.1 MB (proven fits, R10-R17)

  if (ws_size >= REQ) {
    // ---- MFMA path layout (unchanged) ----
    float* lbl     = ws;                     // 212992
    float* pnorm   = lbl + NLBL * CDIM;      // 100352
    float* lnorm   = pnorm + 100352;         // 1024
    float* ctx_all = lnorm + 1024;           // 212992
    float* ctx_gm  = ctx_all + NLBL * CDIM;  // 65536
    float* ctx_sm  = ctx_gm + NGENRE * CDIM; // 131072
    float* ctx_sg  = ctx_sm + NSUB * CDIM;   // 131072
    float* part_s  = ctx_sg + NSUB * CDIM;   // 756288
    int*   part_i  = (int*)(part_s + (size_t)NLBL * NCH4 * KPS4);
    unsigned short* packed = (unsigned short*)(part_i + (size_t)NLBL * NCH4 * KPS4);
    unsigned short* lblbf  = packed + (size_t)NPATCH * CDIM;
    float* onorm_m = (float*)(lblbf + (size_t)NLBL * CDIM);  // 64
    float* onorm_g = onorm_m + NMOOD;                        // 256

    k_prep3<<<2048, 256, 0, stream>>>(patch, mood_emb, genre_emb, sub_emb,
                                      packed, pnorm, lbl, lblbf, lnorm);
    k_screen_mfma<<<13 * NCH4, 256, 0, stream>>>(lblbf, packed, pnorm,
                                                 part_s, part_i);
    k_merge_mfma<<<NLBL, 256, 0, stream>>>(part_s, part_i, patch, lbl, pnorm,
                                           lnorm, ctx_all, mood_emb, Wm_w,
                                           Wm_b, lnm_g, lnm_b, out, onorm_m);
    k_genre<<<NGENRE, 256, 0, stream>>>(genre_emb, out, lnorm, onorm_m,
                                        ctx_all, Wg_w, Wg_b, lng_g, lng_b,
                                        ctx_gm, out, onorm_g);
    k_sub<<<NSUB, 256, 0, stream>>>(sub_emb, out, out + NMOOD * CDIM, lnorm,
                                    onorm_m, onorm_g, ctx_all, Ws_w, Ws_b,
                                    lns_g, lns_b, ctx_sm, ctx_sg, out);
  } else {
    // ---- R4 fallback layout ----
    float* lbl    = ws;
    float* pnorm  = lbl + NLBL * CDIM;
    float* lnorm  = pnorm + 100352;
    float* part_s = lnorm + 1024;
    int*   part_i = (int*)(part_s + NLBL * NCHUNK * KP);
    float* ctx_all = part_s + 2 * NLBL * NCHUNK * KP;
    float* ctx_gm  = ctx_all + NLBL * CDIM;
    float* ctx_sm  = ctx_gm + NGENRE * CDIM;
    float* ctx_sg  = ctx_sm + NSUB * CDIM;
    float* onorm_m = ctx_sg + NSUB * CDIM;
    float* onorm_g = onorm_m + NMOOD;

    k_concat_labels<<<NLBL, 256, 0, stream>>>(mood_emb, genre_emb, sub_emb, lbl);
    k_norms_np<<<512, 256, 0, stream>>>(patch, NPATCH, pnorm);
    k_norms_np<<<4, 256, 0, stream>>>(lbl, NLBL, lnorm);
    dim3 gscr(NCHUNK, NLBL / BLK);
    k_screen_f32<<<gscr, 256, 0, stream>>>(lbl, patch, pnorm, lnorm, part_s, part_i);
    k_merge_f32<<<NLBL, 256, 0, stream>>>(part_s, part_i, patch, lbl, ctx_all);
    k_level_out<<<NMOOD, 256, 0, stream>>>(mood_emb, ctx_all, nullptr, nullptr, 2,
                                           Wm_w, Wm_b, lnm_g, lnm_b, out, onorm_m);
    k_small_agg<<<NGENRE, 256, 0, stream>>>(genre_emb, out, lnorm + NMOOD,
                                            onorm_m, NMOOD, 4, ctx_gm);
    k_level_out<<<NGENRE, 256, 0, stream>>>(genre_emb, ctx_all + NMOOD * CDIM,
                                            ctx_gm, nullptr, 3, Wg_w, Wg_b,
                                            lng_g, lng_b, out + NMOOD * CDIM,
                                            onorm_g);
    k_small_agg<<<NSUB, 256, 0, stream>>>(sub_emb, out, lnorm + NMOOD + NGENRE,
                                          onorm_m, NMOOD, 3, ctx_sm);
    k_small_agg<<<NSUB, 256, 0, stream>>>(sub_emb, out + NMOOD * CDIM,
                                          lnorm + NMOOD + NGENRE, onorm_g,
                                          NGENRE, 4, ctx_sg);
    k_level_out<<<NSUB, 256, 0, stream>>>(sub_emb,
                                          ctx_all + (NMOOD + NGENRE) * CDIM,
                                          ctx_sm, ctx_sg, 4, Ws_w, Ws_b, lns_g,
                                          lns_b, out + (NMOOD + NGENRE) * CDIM,
                                          nullptr);
  }
}